// Round 19
// baseline (612.217 us; speedup 1.0000x reference)
//
#include <hip/hip_runtime.h>

// StochasticRegionalConvolution — fused MFMA conv, cross-tile pipeline.
// out[b,co,p,q] = coeff(p,q) * sum_{ci,kh,kw} x[b,ci,p+kh,q+kw] * W[co,ci,kh,kw]
//
// K1: coeff map (256x256 f32)                     -> d_ws[0, 256KB)
// K2: weight transform to MFMA A-frag order, bf16 -> d_ws[256KB, 328KB)
// K3: fused conv: block = 32x32 region = 4 stacked 8x32 tiles (R16 inner
//     schedule per tile). va/vb register arrays reused across tiles; next
//     tile's 24 loads issued at the mid-tile barrier and hidden under
//     phases 9-17 + epilogue -> steady-state staging wait = 0. Dedicated
//     epilogue LDS buffer; 2 raw barriers per tile (lgkm-only, VMEM flies).

typedef short short8 __attribute__((ext_vector_type(8)));
typedef float floatx4 __attribute__((ext_vector_type(4)));
typedef unsigned int uint4v __attribute__((ext_vector_type(4)));

#define OUTR 62

// raw barrier: waits LDS ops only; leaves VMEM loads in flight
#define BAR() do {                                              \
    asm volatile("s_waitcnt lgkmcnt(0)" ::: "memory");          \
    __builtin_amdgcn_s_barrier();                               \
    asm volatile("" ::: "memory");                              \
} while (0)

__device__ inline unsigned f2bf_pack(float lo, float hi) {
    unsigned ul = __builtin_bit_cast(unsigned, lo);
    unsigned uh = __builtin_bit_cast(unsigned, hi);
    ul = (ul + 0x7FFFu + ((ul >> 16) & 1u)) >> 16;   // RNE
    uh = (uh + 0x7FFFu + ((uh >> 16) & 1u)) >> 16;
    return ul | (uh << 16);
}

__global__ void srconv_coeff_kernel(const int* __restrict__ h_idx,
                                    const int* __restrict__ w_idx,
                                    const float* __restrict__ lam,
                                    int T, float* __restrict__ coeff) {
    int p = blockIdx.x;
    int q = threadIdx.x;
    float c = 0.f;
    for (int t = 0; t < T; ++t) {
        int dh = p - h_idx[t];
        int dw = q - w_idx[t];
        if (dh >= 0 && dh < OUTR && dw >= 0 && dw < OUTR) c += lam[t];
    }
    coeff[(p << 8) + q] = c * (1.0f / 16.0f);
}

__global__ void srconv_wtrans_kernel(const float* __restrict__ wgt,
                                     uint4v* __restrict__ afrag) {
    int id = blockIdx.x * 256 + threadIdx.x;      // [0, 72*64)
    int l  = id & 63;
    int fi = id >> 6;                             // (kk*2+cb)*4 + m
    int m  = fi & 3;
    int cb = (fi >> 2) & 1;
    int kk = fi >> 3;
    int co  = m * 16 + (l & 15);
    int ci0 = cb * 32 + (l >> 4) * 8;
    float w[8];
#pragma unroll
    for (int j = 0; j < 8; ++j)
        w[j] = wgt[(co * 64 + ci0 + j) * 9 + kk];
    uint4v d;
    d.x = f2bf_pack(w[0], w[1]);
    d.y = f2bf_pack(w[2], w[3]);
    d.z = f2bf_pack(w[4], w[5]);
    d.w = f2bf_pack(w[6], w[7]);
    afrag[id] = d;
}

// ---- staging helpers (R16's proven decode; cp = ci-pair) -------------------
__device__ __forceinline__ void issue_half(const float* __restrict__ xb,
                                           int P0, int Q0, int tid, int ciBase,
                                           floatx4 (&v)[6][2]) {
#pragma unroll
    for (int r = 0; r < 6; ++r) {
        int u  = r * 256 + tid;
        int uc = u < 1440 ? u : 1439;
        int cp    = uc / 90;
        int rem   = uc - cp * 90;
        int row   = rem / 9;
        int chunk = rem - row * 9;
        int gr    = min(P0 + row, 255);
        int gcb   = min(Q0 + (chunk << 2), 252);
        const float* xp = xb + ((ciBase + cp) << 17) + (gr << 8) + gcb;
        v[r][0] = *(const floatx4*)(xp);
        v[r][1] = *(const floatx4*)(xp + 65536);
    }
}

__device__ __forceinline__ void write_half(unsigned* __restrict__ xs, int off,
                                           int tid, floatx4 (&v)[6][2]) {
#pragma unroll
    for (int r = 0; r < 6; ++r) {
        int u  = r * 256 + tid;
        int uc = u < 1440 ? u : 1439;
        int cp    = uc / 90;
        int rem   = uc - cp * 90;
        int row   = rem / 9;
        int chunk = rem - row * 9;
        int c4 = chunk << 2;
#pragma unroll
        for (int j = 0; j < 4; ++j) {
            if (u < 1440 && c4 + j < 34) {
                int pix = row * 34 + c4 + j;
                int slot = cp ^ (((pix >> 1) & 3) << 2);
                xs[off + (pix << 4) + slot] = f2bf_pack(v[r][0][j], v[r][1][j]);
            }
        }
    }
}

// LDS xs[cb][pix 0..339][16 u32], slot = cp ^ (((pix>>1)&3)<<2).
// B-frag (kg): b128 at group kg ^ ((pix>>1)&3) -> ci 8kg..8kg+7 in order.
__launch_bounds__(256, 2)
__global__ void srconv_fused_kernel(const float* __restrict__ x,
                                    const float* __restrict__ coeff,
                                    const short8* __restrict__ afrag,
                                    float* __restrict__ out) {
    __shared__ __align__(16) unsigned xs[2 * 340 * 16];   // 43,520 B
    __shared__ float ep[8 * 576];                         // 18,432 B

    const int tid  = threadIdx.x;
    const int lane = tid & 63;
    const int wv   = tid >> 6;            // 0..3 -> p-rows {2wv, 2wv+1}
    const int l15  = lane & 15;
    const int kg   = lane >> 4;

    // bijective XCD swizzle: 1024 blocks, 8 XCDs x 128 -> 2 batches per XCD
    const unsigned bid = blockIdx.x;
    const unsigned swz = (bid & 7) * 128 + (bid >> 3);
    const int b  = swz >> 6;              // 16 batches
    const int g  = swz & 63;              // 8 row-groups x 8 col-groups
    const int G0 = (g >> 3) << 5;         // region rows [G0, G0+32)
    const int Q0 = (g & 7) << 5;          // region cols [Q0, Q0+32)

    // ---- region skip vote: 32x32 coeffs, 4 per thread ----
    float cm = 0.f;
#pragma unroll
    for (int i = 0; i < 4; ++i) {
        int u = i * 256 + tid;
        cm = fmaxf(cm, coeff[((G0 + (u >> 5)) << 8) + Q0 + (u & 31)]);
    }
    if (__syncthreads_count(cm != 0.f) == 0) {
        const floatx4 z = (floatx4){0.f, 0.f, 0.f, 0.f};
        for (int u = tid; u < 64 * 32 * 8; u += 256) {
            int q4 = u & 7;
            int pr = (u >> 3) & 31;
            int co = u >> 8;
            *(floatx4*)(out + (((b << 6) + co) << 16) +
                        ((G0 + pr) << 8) + Q0 + (q4 << 2)) = z;
        }
        return;
    }

    const float* xb = x + ((size_t)b << 22);
    const int co_l = lane >> 3;           // epilogue lane mapping
    const int q4   = lane & 7;

    // ---- prologue: tile 0 staged the R16 way ----
    floatx4 va[6][2], vb[6][2];
    issue_half(xb, G0, Q0, tid, 0, va);

    short8 areg[2][4];                    // phases t=0,1: kk0/kk1, cb0
#pragma unroll
    for (int m = 0; m < 4; ++m) {
        areg[0][m] = afrag[(0 + m) * 64 + lane];
        areg[1][m] = afrag[(8 + m) * 64 + lane];
    }

    issue_half(xb, G0, Q0, tid, 16, vb);
    write_half(xs, 0, tid, va);           // waits va only; vb stays in flight
    BAR();

    for (int s = 0; s < 4; ++s) {
        const int P0  = G0 + (s << 3);
        const int prb = P0 + (wv << 1);

        float cf[2][2];
#pragma unroll
        for (int p = 0; p < 2; ++p)
#pragma unroll
            for (int h = 0; h < 2; ++h)
                cf[p][h] = coeff[((prb + p) << 8) + Q0 + (h << 4) + l15];

        floatx4 acc[4][2][2];
#pragma unroll
        for (int m = 0; m < 4; ++m)
#pragma unroll
            for (int p = 0; p < 2; ++p)
#pragma unroll
                for (int h = 0; h < 2; ++h)
                    acc[m][p][h] = (floatx4){0.f, 0.f, 0.f, 0.f};

        // ---- phases 0..8 (cb = 0, xs half 0) ----
#pragma unroll
        for (int t = 0; t < 9; ++t) {
            const int kh = t / 3;
            const int kw = t - kh * 3;
            const int cur = t & 1;
            short8 bf[2][2];
#pragma unroll
            for (int p = 0; p < 2; ++p)
#pragma unroll
                for (int h = 0; h < 2; ++h) {
                    int prl = (wv << 1) + p + kh;
                    int cl  = (h << 4) + l15 + kw;
                    int pix = prl * 34 + cl;
                    int off = (pix << 4) +
                              ((kg << 2) ^ (((pix >> 1) & 3) << 2));
                    bf[p][h] = *(const short8*)(&xs[off]);
                }
#pragma unroll
            for (int m = 0; m < 4; ++m)
#pragma unroll
                for (int p = 0; p < 2; ++p)
#pragma unroll
                    for (int h = 0; h < 2; ++h)
                        acc[m][p][h] = __builtin_amdgcn_mfma_f32_16x16x32_bf16(
                            areg[cur][m], bf[p][h], acc[m][p][h], 0, 0, 0);
            {   // prefetch phase (t+2) % 18 — continuous across tiles
                const int tn  = (t + 2) % 18;
                const int cbn = tn / 9;
                const int kkn = tn - cbn * 9;
#pragma unroll
                for (int m = 0; m < 4; ++m)
                    areg[cur][m] =
                        afrag[((((kkn << 1) + cbn) << 2) + m) * 64 + lane];
            }
        }

        write_half(xs, 5440, tid, vb);    // waits vb; next-tile loads not yet issued
        BAR();

        if (s < 3) {                      // issue next tile's loads; they fly
            issue_half(xb, P0 + 8, Q0, tid, 0, va);
            issue_half(xb, P0 + 8, Q0, tid, 16, vb);
            __builtin_amdgcn_sched_barrier(0);   // pin: don't sink the issues
        }

        // ---- phases 9..17 (cb = 1, xs half 1) ----
#pragma unroll
        for (int t = 9; t < 18; ++t) {
            const int kk = t - 9;
            const int kh = kk / 3;
            const int kw = kk - kh * 3;
            const int cur = t & 1;
            short8 bf[2][2];
#pragma unroll
            for (int p = 0; p < 2; ++p)
#pragma unroll
                for (int h = 0; h < 2; ++h) {
                    int prl = (wv << 1) + p + kh;
                    int cl  = (h << 4) + l15 + kw;
                    int pix = prl * 34 + cl;
                    int off = 5440 + (pix << 4) +
                              ((kg << 2) ^ (((pix >> 1) & 3) << 2));
                    bf[p][h] = *(const short8*)(&xs[off]);
                }
#pragma unroll
            for (int m = 0; m < 4; ++m)
#pragma unroll
                for (int p = 0; p < 2; ++p)
#pragma unroll
                    for (int h = 0; h < 2; ++h)
                        acc[m][p][h] = __builtin_amdgcn_mfma_f32_16x16x32_bf16(
                            areg[cur][m], bf[p][h], acc[m][p][h], 0, 0, 0);
            {
                const int tn  = (t + 2) % 18;
                const int cbn = tn / 9;
                const int kkn = tn - cbn * 9;
#pragma unroll
                for (int m = 0; m < 4; ++m)
                    areg[cur][m] =
                        afrag[((((kkn << 1) + cbn) << 2) + m) * 64 + lane];
            }
        }

        // xs half-0 readers finished before the mid barrier -> write now,
        // overlapped with the epilogue below (different LDS buffer).
        if (s < 3) write_half(xs, 0, tid, va);

        // ---- epilogue: per-wave slabs in ep, full-line float4 stores ----
        // D layout (m89): col = lane&15 -> q, row = (lane>>4)*4+reg -> co16
#pragma unroll
        for (int p = 0; p < 2; ++p) {
            const int pr = prb + p;
#pragma unroll
            for (int m = 0; m < 4; ++m) {
                float* eps = ep + (((wv << 1) + (m & 1)) * 576);
#pragma unroll
                for (int h = 0; h < 2; ++h)
#pragma unroll
                    for (int reg = 0; reg < 4; ++reg)
                        eps[((kg << 2) + reg) * 36 + (h << 4) + l15] =
                            acc[m][p][h][reg] * cf[p][h];
                // wave-internal RAW through LDS: compiler lgkmcnt orders
#pragma unroll
                for (int j = 0; j < 2; ++j) {
                    const floatx4 v = *reinterpret_cast<const floatx4*>(
                        &eps[(co_l + (j << 3)) * 36 + (q4 << 2)]);
                    const int co = (m << 4) + co_l + (j << 3);
                    *(floatx4*)(out + (((b << 6) + co) << 16) +
                                (pr << 8) + Q0 + (q4 << 2)) = v;
                }
            }
        }

        if (s < 3) BAR();                 // xs half-0 (next tile) visible to all
    }
}

extern "C" void kernel_launch(void* const* d_in, const int* in_sizes, int n_in,
                              void* d_out, int out_size, void* d_ws, size_t ws_size,
                              hipStream_t stream) {
    const float* x     = (const float*)d_in[0];
    const float* wgt   = (const float*)d_in[1];
    const int*   h_idx = (const int*)d_in[2];
    const int*   w_idx = (const int*)d_in[3];
    const float* lam   = (const float*)d_in[4];
    float*       out   = (float*)d_out;
    float*       coeff = (float*)d_ws;                        // 256 KB
    char*        af_b  = (char*)d_ws + 65536 * sizeof(float); // 72 KB
    const int    T     = in_sizes[2];

    srconv_coeff_kernel<<<256, 256, 0, stream>>>(h_idx, w_idx, lam, T, coeff);
    srconv_wtrans_kernel<<<18, 256, 0, stream>>>(wgt, (uint4v*)af_b);
    // 1024 blocks = (8x8 regions of 32x32) x 16 batches, XCD-swizzled
    srconv_fused_kernel<<<1024, 256, 0, stream>>>(
        x, coeff, (const short8*)af_b, out);
}

// Round 20
// 172.225 us; speedup vs baseline: 3.5547x; 3.5547x over previous
//
#include <hip/hip_runtime.h>

// StochasticRegionalConvolution — fused MFMA conv
// (R16 + rolled phase loops (unroll 2) + s_setprio around MFMA clusters).
// out[b,co,p,q] = coeff(p,q) * sum_{ci,kh,kw} x[b,ci,p+kh,q+kw] * W[co,ci,kh,kw]
//
// K1: coeff map (256x256 f32)                     -> d_ws[0, 256KB)
// K2: weight transform to MFMA A-frag order, bf16 -> d_ws[256KB, 328KB)
// K3: fused conv: 8x32 pixel tile, 256 thr / 4 waves. ALL 24 staging loads
//     issued upfront; half-0 packed+written, phases 0-8 while half-1 loads
//     fly; half-1 written at the 9-phase boundary. Phase loops rolled
//     (#pragma unroll 2 keeps areg parity static) to shrink code footprint;
//     setprio(1) around MFMA clusters (T5; schedule is phase-diverse).

typedef short short8 __attribute__((ext_vector_type(8)));
typedef float floatx4 __attribute__((ext_vector_type(4)));
typedef unsigned int uint4v __attribute__((ext_vector_type(4)));

#define OUTR 62

__device__ inline unsigned f2bf_pack(float lo, float hi) {
    unsigned ul = __builtin_bit_cast(unsigned, lo);
    unsigned uh = __builtin_bit_cast(unsigned, hi);
    ul = (ul + 0x7FFFu + ((ul >> 16) & 1u)) >> 16;   // RNE
    uh = (uh + 0x7FFFu + ((uh >> 16) & 1u)) >> 16;
    return ul | (uh << 16);
}

__global__ void srconv_coeff_kernel(const int* __restrict__ h_idx,
                                    const int* __restrict__ w_idx,
                                    const float* __restrict__ lam,
                                    int T, float* __restrict__ coeff) {
    int p = blockIdx.x;
    int q = threadIdx.x;
    float c = 0.f;
    for (int t = 0; t < T; ++t) {
        int dh = p - h_idx[t];
        int dw = q - w_idx[t];
        if (dh >= 0 && dh < OUTR && dw >= 0 && dw < OUTR) c += lam[t];
    }
    coeff[(p << 8) + q] = c * (1.0f / 16.0f);
}

__global__ void srconv_wtrans_kernel(const float* __restrict__ wgt,
                                     uint4v* __restrict__ afrag) {
    int id = blockIdx.x * 256 + threadIdx.x;      // [0, 72*64)
    int l  = id & 63;
    int fi = id >> 6;                             // (kk*2+cb)*4 + m
    int m  = fi & 3;
    int cb = (fi >> 2) & 1;
    int kk = fi >> 3;
    int co  = m * 16 + (l & 15);
    int ci0 = cb * 32 + (l >> 4) * 8;
    float w[8];
#pragma unroll
    for (int j = 0; j < 8; ++j)
        w[j] = wgt[(co * 64 + ci0 + j) * 9 + kk];
    uint4v d;
    d.x = f2bf_pack(w[0], w[1]);
    d.y = f2bf_pack(w[2], w[3]);
    d.z = f2bf_pack(w[4], w[5]);
    d.w = f2bf_pack(w[6], w[7]);
    afrag[id] = d;
}

// LDS xs[cb][pix 0..339][16 u32 ci-pairs], slot = cp ^ (((pix>>1)&3)<<2).
// B-frag (kg): b128 at slot16 = kg ^ ((pix>>1)&3) -> ci 8kg..8kg+7 in order.
__launch_bounds__(256, 2)
__global__ void srconv_fused_kernel(const float* __restrict__ x,
                                    const float* __restrict__ coeff,
                                    const short8* __restrict__ afrag,
                                    float* __restrict__ out) {
    __shared__ __align__(16) unsigned xs[2 * 340 * 16];   // 43,520 B

    const int tid  = threadIdx.x;
    const int lane = tid & 63;
    const int wv   = tid >> 6;            // 0..3 -> p-rows {2wv, 2wv+1}
    const int l15  = lane & 15;
    const int kg   = lane >> 4;

    // bijective XCD swizzle: 4096 blocks, 8 XCDs x 512 -> 2 batches per XCD
    const unsigned bid = blockIdx.x;
    const unsigned swz = (bid & 7) * 512 + (bid >> 3);
    const int b    = swz >> 8;
    const int tile = swz & 255;           // 32 p-tiles x 8 q-tiles
    const int P0   = (tile >> 3) << 3;
    const int Q0   = (tile & 7) << 5;

    // ---- tile skip vote ----
    float myc = coeff[((P0 + (tid >> 5)) << 8) + Q0 + (tid & 31)];
    if (__syncthreads_count(myc != 0.f) == 0) {
        const floatx4 z = (floatx4){0.f, 0.f, 0.f, 0.f};
        for (int u = tid; u < 64 * 8 * 8; u += 256) {
            int q4 = u & 7;
            int pr = (u >> 3) & 7;
            int co = u >> 6;
            *(floatx4*)(out + (((b << 6) + co) << 16) +
                        ((P0 + pr) << 8) + Q0 + (q4 << 2)) = z;
        }
        return;
    }

    const int prb = P0 + (wv << 1);

    // ---- hoisted epilogue coeff loads (oldest in VMEM FIFO) ----
    float cf[2][2];
#pragma unroll
    for (int p = 0; p < 2; ++p)
#pragma unroll
        for (int h = 0; h < 2; ++h)
            cf[p][h] = coeff[((prb + p) << 8) + Q0 + (h << 4) + l15];

    const float* xb = x + ((size_t)b << 22);

    // ---- batched staging (R16): ISSUE all 24, WRITE half-0, barrier,
    //      compute 0-8 (vb flies), WRITE half-1, barrier, compute 9-17.
    floatx4 va[6][2], vb[6][2];

#pragma unroll
    for (int r = 0; r < 6; ++r) {         // ISSUE half 0
        int u  = r * 256 + tid;
        int uc = u < 1440 ? u : 1439;
        int cp    = uc / 90;
        int rem   = uc - cp * 90;
        int row   = rem / 9;
        int chunk = rem - row * 9;
        int gr    = min(P0 + row, 255);
        int gcb   = min(Q0 + (chunk << 2), 252);
        const float* xp = xb + (cp << 17) + (gr << 8) + gcb;
        va[r][0] = *(const floatx4*)(xp);
        va[r][1] = *(const floatx4*)(xp + 65536);
    }

    // areg preload (phases t=0,1) — before vb in the VMEM FIFO
    short8 areg[2][4];
#pragma unroll
    for (int m = 0; m < 4; ++m) {
        areg[0][m] = afrag[(0 + m) * 64 + lane];
        areg[1][m] = afrag[(8 + m) * 64 + lane];
    }

#pragma unroll
    for (int r = 0; r < 6; ++r) {         // ISSUE half 1
        int u  = r * 256 + tid;
        int uc = u < 1440 ? u : 1439;
        int cp    = uc / 90;
        int rem   = uc - cp * 90;
        int row   = rem / 9;
        int chunk = rem - row * 9;
        int gr    = min(P0 + row, 255);
        int gcb   = min(Q0 + (chunk << 2), 252);
        const float* xp = xb + ((16 + cp) << 17) + (gr << 8) + gcb;
        vb[r][0] = *(const floatx4*)(xp);
        vb[r][1] = *(const floatx4*)(xp + 65536);
    }

#pragma unroll
    for (int r = 0; r < 6; ++r) {         // WRITE half 0 (compiler waits va only)
        int u  = r * 256 + tid;
        int uc = u < 1440 ? u : 1439;
        int cp    = uc / 90;
        int rem   = uc - cp * 90;
        int row   = rem / 9;
        int chunk = rem - row * 9;
        int c4 = chunk << 2;
#pragma unroll
        for (int j = 0; j < 4; ++j) {
            if (u < 1440 && c4 + j < 34) {
                int pix = row * 34 + c4 + j;
                int slot = cp ^ (((pix >> 1) & 3) << 2);
                xs[(pix << 4) + slot] = f2bf_pack(va[r][0][j], va[r][1][j]);
            }
        }
    }
    __syncthreads();                      // half-0 ready

    floatx4 acc[4][2][2];                 // [m: co16][p: row][h: q-half]
#pragma unroll
    for (int m = 0; m < 4; ++m)
#pragma unroll
        for (int p = 0; p < 2; ++p)
#pragma unroll
            for (int h = 0; h < 2; ++h)
                acc[m][p][h] = (floatx4){0.f, 0.f, 0.f, 0.f};

    // ---- phases 0..8 (cb = 0) — ROLLED (unroll 2: areg parity static) ----
#pragma unroll 2
    for (int t = 0; t < 9; ++t) {
        const int kh = t / 3;
        const int kw = t - kh * 3;
        const int cur = t & 1;

        short8 bf[2][2];
#pragma unroll
        for (int p = 0; p < 2; ++p)
#pragma unroll
            for (int h = 0; h < 2; ++h) {
                int prl = (wv << 1) + p + kh;          // 0..9
                int cl  = (h << 4) + l15 + kw;         // 0..33
                int pix = prl * 34 + cl;
                int off = (pix << 4) +
                          ((kg << 2) ^ (((pix >> 1) & 3) << 2));
                bf[p][h] = *(const short8*)(&xs[off]);
            }
        __builtin_amdgcn_s_setprio(1);
#pragma unroll
        for (int m = 0; m < 4; ++m)
#pragma unroll
            for (int p = 0; p < 2; ++p)
#pragma unroll
                for (int h = 0; h < 2; ++h)
                    acc[m][p][h] = __builtin_amdgcn_mfma_f32_16x16x32_bf16(
                        areg[cur][m], bf[p][h], acc[m][p][h], 0, 0, 0);
        __builtin_amdgcn_s_setprio(0);

        {   // prefetch phase t+2 (cb-aware crossing into cb=1)
            const int tn  = t + 2;
            const int cbn = tn / 9;
            const int kkn = tn - cbn * 9;
#pragma unroll
            for (int m = 0; m < 4; ++m)
                areg[cur][m] =
                    afrag[((((kkn << 1) + cbn) << 2) + m) * 64 + lane];
        }
    }

    // ---- WRITE half 1 ----
#pragma unroll
    for (int r = 0; r < 6; ++r) {
        int u  = r * 256 + tid;
        int uc = u < 1440 ? u : 1439;
        int cp    = uc / 90;
        int rem   = uc - cp * 90;
        int row   = rem / 9;
        int chunk = rem - row * 9;
        int c4 = chunk << 2;
#pragma unroll
        for (int j = 0; j < 4; ++j) {
            if (u < 1440 && c4 + j < 34) {
                int pix = row * 34 + c4 + j;
                int slot = cp ^ (((pix >> 1) & 3) << 2);
                xs[5440 + (pix << 4) + slot] =
                    f2bf_pack(vb[r][0][j], vb[r][1][j]);
            }
        }
    }
    __syncthreads();                      // half-1 ready

    // ---- phases 9..17 (cb = 1) — ROLLED ----
#pragma unroll 2
    for (int t = 9; t < 18; ++t) {
        const int kk = t - 9;
        const int kh = kk / 3;
        const int kw = kk - kh * 3;
        const int cur = t & 1;

        short8 bf[2][2];
#pragma unroll
        for (int p = 0; p < 2; ++p)
#pragma unroll
            for (int h = 0; h < 2; ++h) {
                int prl = (wv << 1) + p + kh;
                int cl  = (h << 4) + l15 + kw;
                int pix = prl * 34 + cl;
                int off = 5440 + (pix << 4) +
                          ((kg << 2) ^ (((pix >> 1) & 3) << 2));
                bf[p][h] = *(const short8*)(&xs[off]);
            }
        __builtin_amdgcn_s_setprio(1);
#pragma unroll
        for (int m = 0; m < 4; ++m)
#pragma unroll
            for (int p = 0; p < 2; ++p)
#pragma unroll
                for (int h = 0; h < 2; ++h)
                    acc[m][p][h] = __builtin_amdgcn_mfma_f32_16x16x32_bf16(
                        areg[cur][m], bf[p][h], acc[m][p][h], 0, 0, 0);
        __builtin_amdgcn_s_setprio(0);

        if (t < 16) {
            const int tn  = t + 2;
            const int kkn = tn - 9;
#pragma unroll
            for (int m = 0; m < 4; ++m)
                areg[cur][m] =
                    afrag[((((kkn << 1) + 1) << 2) + m) * 64 + lane];
        }
    }
    __syncthreads();                      // all waves done reading xs

    // ---- epilogue: per-wave ping-pong slabs overlaid on xs, no barriers ----
    // D layout (m89): col = lane&15 -> q, row = (lane>>4)*4+reg -> co-within-16
    float* epb = reinterpret_cast<float*>(xs);
    const int co_l = lane >> 3;           // 0..7
    const int q4   = lane & 7;

#pragma unroll
    for (int p = 0; p < 2; ++p) {
        const int pr = prb + p;
#pragma unroll
        for (int m = 0; m < 4; ++m) {
            float* ep = epb + (((wv << 1) + (m & 1)) * 576);
#pragma unroll
            for (int h = 0; h < 2; ++h)
#pragma unroll
                for (int reg = 0; reg < 4; ++reg)
                    ep[((kg << 2) + reg) * 36 + (h << 4) + l15] =
                        acc[m][p][h][reg] * cf[p][h];
            // wave-internal RAW through LDS: compiler-inserted lgkmcnt orders
#pragma unroll
            for (int j = 0; j < 2; ++j) {
                const floatx4 v = *reinterpret_cast<const floatx4*>(
                    &ep[(co_l + (j << 3)) * 36 + (q4 << 2)]);
                const int co = (m << 4) + co_l + (j << 3);
                *(floatx4*)(out + (((b << 6) + co) << 16) +
                            (pr << 8) + Q0 + (q4 << 2)) = v;
            }
        }
    }
}

extern "C" void kernel_launch(void* const* d_in, const int* in_sizes, int n_in,
                              void* d_out, int out_size, void* d_ws, size_t ws_size,
                              hipStream_t stream) {
    const float* x     = (const float*)d_in[0];
    const float* wgt   = (const float*)d_in[1];
    const int*   h_idx = (const int*)d_in[2];
    const int*   w_idx = (const int*)d_in[3];
    const float* lam   = (const float*)d_in[4];
    float*       out   = (float*)d_out;
    float*       coeff = (float*)d_ws;                        // 256 KB
    char*        af_b  = (char*)d_ws + 65536 * sizeof(float); // 72 KB
    const int    T     = in_sizes[2];

    srconv_coeff_kernel<<<256, 256, 0, stream>>>(h_idx, w_idx, lam, T, coeff);
    srconv_wtrans_kernel<<<18, 256, 0, stream>>>(wgt, (uint4v*)af_b);
    // 4096 blocks = (32 p-tiles x 8 q-tiles) x 16 batches, XCD-swizzled
    srconv_fused_kernel<<<4096, 256, 0, stream>>>(
        x, coeff, (const short8*)af_b, out);
}

// Round 21
// 169.760 us; speedup vs baseline: 3.6064x; 1.0145x over previous
//
#include <hip/hip_runtime.h>

// StochasticRegionalConvolution — fused MFMA conv
// (R20 champion + A-fragments staged in LDS: hot loop is pure LDS+MFMA).
// out[b,co,p,q] = coeff(p,q) * sum_{ci,kh,kw} x[b,ci,p+kh,q+kw] * W[co,ci,kh,kw]
//
// K1: coeff map (256x256 f32)                     -> d_ws[0, 256KB)
// K2: weight transform to MFMA A-frag order, bf16 -> d_ws[256KB, 328KB)
// K3: fused conv: 8x32 pixel tile, 256 thr / 4 waves. Batched staging:
//     ISSUE af0+va -> WRITE af0,va (waits those only) -> ISSUE vb+af1 ->
//     barrier -> phases 0-8 (pure LDS+MFMA; vb/af1 fly) -> barrier ->
//     WRITE vb,af1 -> barrier -> phases 9-17 -> epilogue.
//     A-table cyclic 72KB global sweep (L1-thrash, ~250cy/load x 72/thread)
//     replaced by conflict-free ds_read_b128. LDS 80.3KB -> 2 blocks/CU.

typedef short short8 __attribute__((ext_vector_type(8)));
typedef float floatx4 __attribute__((ext_vector_type(4)));
typedef unsigned int uint4v __attribute__((ext_vector_type(4)));

#define OUTR 62

__device__ inline unsigned f2bf_pack(float lo, float hi) {
    unsigned ul = __builtin_bit_cast(unsigned, lo);
    unsigned uh = __builtin_bit_cast(unsigned, hi);
    ul = (ul + 0x7FFFu + ((ul >> 16) & 1u)) >> 16;   // RNE
    uh = (uh + 0x7FFFu + ((uh >> 16) & 1u)) >> 16;
    return ul | (uh << 16);
}

__global__ void srconv_coeff_kernel(const int* __restrict__ h_idx,
                                    const int* __restrict__ w_idx,
                                    const float* __restrict__ lam,
                                    int T, float* __restrict__ coeff) {
    int p = blockIdx.x;
    int q = threadIdx.x;
    float c = 0.f;
    for (int t = 0; t < T; ++t) {
        int dh = p - h_idx[t];
        int dw = q - w_idx[t];
        if (dh >= 0 && dh < OUTR && dw >= 0 && dw < OUTR) c += lam[t];
    }
    coeff[(p << 8) + q] = c * (1.0f / 16.0f);
}

__global__ void srconv_wtrans_kernel(const float* __restrict__ wgt,
                                     uint4v* __restrict__ afrag) {
    int id = blockIdx.x * 256 + threadIdx.x;      // [0, 72*64)
    int l  = id & 63;
    int fi = id >> 6;                             // (kk*2+cb)*4 + m
    int m  = fi & 3;
    int cb = (fi >> 2) & 1;
    int kk = fi >> 3;
    int co  = m * 16 + (l & 15);
    int ci0 = cb * 32 + (l >> 4) * 8;
    float w[8];
#pragma unroll
    for (int j = 0; j < 8; ++j)
        w[j] = wgt[(co * 64 + ci0 + j) * 9 + kk];
    uint4v d;
    d.x = f2bf_pack(w[0], w[1]);
    d.y = f2bf_pack(w[2], w[3]);
    d.z = f2bf_pack(w[4], w[5]);
    d.w = f2bf_pack(w[6], w[7]);
    afrag[id] = d;
}

// LDS xs[cb][pix 0..339][16 u32 ci-pairs], slot = cp ^ (((pix>>1)&3)<<2).
// B-frag (kg): b128 at slot16 = kg ^ ((pix>>1)&3) -> ci 8kg..8kg+7 in order.
// af_lds[kk*256 + m*64 + lane] (uint4v units): one cb-half's A-table,
// linear -> both staging writes and per-phase reads are conflict-free.
__launch_bounds__(256, 2)
__global__ void srconv_fused_kernel(const float* __restrict__ x,
                                    const float* __restrict__ coeff,
                                    const uint4v* __restrict__ afrag,
                                    float* __restrict__ out) {
    __shared__ __align__(16) unsigned xs[2 * 340 * 16];   // 43,520 B
    __shared__ __align__(16) uint4v af_lds[2304];         // 36,864 B

    const int tid  = threadIdx.x;
    const int lane = tid & 63;
    const int wv   = tid >> 6;            // 0..3 -> p-rows {2wv, 2wv+1}
    const int l15  = lane & 15;
    const int kg   = lane >> 4;

    // bijective XCD swizzle: 4096 blocks, 8 XCDs x 512 -> 2 batches per XCD
    const unsigned bid = blockIdx.x;
    const unsigned swz = (bid & 7) * 512 + (bid >> 3);
    const int b    = swz >> 8;
    const int tile = swz & 255;           // 32 p-tiles x 8 q-tiles
    const int P0   = (tile >> 3) << 3;
    const int Q0   = (tile & 7) << 5;

    // ---- tile skip vote ----
    float myc = coeff[((P0 + (tid >> 5)) << 8) + Q0 + (tid & 31)];
    if (__syncthreads_count(myc != 0.f) == 0) {
        const floatx4 z = (floatx4){0.f, 0.f, 0.f, 0.f};
        for (int u = tid; u < 64 * 8 * 8; u += 256) {
            int q4 = u & 7;
            int pr = (u >> 3) & 7;
            int co = u >> 6;
            *(floatx4*)(out + (((b << 6) + co) << 16) +
                        ((P0 + pr) << 8) + Q0 + (q4 << 2)) = z;
        }
        return;
    }

    const int prb = P0 + (wv << 1);

    // ---- hoisted epilogue coeff loads ----
    float cf[2][2];
#pragma unroll
    for (int p = 0; p < 2; ++p)
#pragma unroll
        for (int h = 0; h < 2; ++h)
            cf[p][h] = coeff[((prb + p) << 8) + Q0 + (h << 4) + l15];

    const float* xb = x + ((size_t)b << 22);

    // ---- staging. x half: 1440 tasks = 16 cp x 10 rows x 9 chunks.
    // A half: 2304 uint4v; element e of half cb sits at global
    //   g = e + (e>>8)*256 + cb*256   (kk = e>>8).
    floatx4 va[6][2], vb[6][2];
    uint4v  vc[9];                        // A-table regs (reused af0 then af1)

#pragma unroll
    for (int i = 0; i < 9; ++i) {         // ISSUE A half 0
        int e = i * 256 + tid;
        vc[i] = afrag[e + ((e >> 8) << 8)];
    }
#pragma unroll
    for (int r = 0; r < 6; ++r) {         // ISSUE x half 0
        int u  = r * 256 + tid;
        int uc = u < 1440 ? u : 1439;
        int cp    = uc / 90;
        int rem   = uc - cp * 90;
        int row   = rem / 9;
        int chunk = rem - row * 9;
        int gr    = min(P0 + row, 255);
        int gcb   = min(Q0 + (chunk << 2), 252);
        const float* xp = xb + (cp << 17) + (gr << 8) + gcb;
        va[r][0] = *(const floatx4*)(xp);
        va[r][1] = *(const floatx4*)(xp + 65536);
    }

#pragma unroll
    for (int i = 0; i < 9; ++i)           // WRITE A half 0 (waits af0 region)
        af_lds[i * 256 + tid] = vc[i];
#pragma unroll
    for (int r = 0; r < 6; ++r) {         // WRITE x half 0 (waits va)
        int u  = r * 256 + tid;
        int uc = u < 1440 ? u : 1439;
        int cp    = uc / 90;
        int rem   = uc - cp * 90;
        int row   = rem / 9;
        int chunk = rem - row * 9;
        int c4 = chunk << 2;
#pragma unroll
        for (int j = 0; j < 4; ++j) {
            if (u < 1440 && c4 + j < 34) {
                int pix = row * 34 + c4 + j;
                int slot = cp ^ (((pix >> 1) & 3) << 2);
                xs[(pix << 4) + slot] = f2bf_pack(va[r][0][j], va[r][1][j]);
            }
        }
    }

#pragma unroll
    for (int r = 0; r < 6; ++r) {         // ISSUE x half 1 (flies over phases 0-8)
        int u  = r * 256 + tid;
        int uc = u < 1440 ? u : 1439;
        int cp    = uc / 90;
        int rem   = uc - cp * 90;
        int row   = rem / 9;
        int chunk = rem - row * 9;
        int gr    = min(P0 + row, 255);
        int gcb   = min(Q0 + (chunk << 2), 252);
        const float* xp = xb + ((16 + cp) << 17) + (gr << 8) + gcb;
        vb[r][0] = *(const floatx4*)(xp);
        vb[r][1] = *(const floatx4*)(xp + 65536);
    }
#pragma unroll
    for (int i = 0; i < 9; ++i) {         // ISSUE A half 1 (flies too)
        int e = i * 256 + tid;
        vc[i] = afrag[e + ((e >> 8) << 8) + 256];
    }
    __syncthreads();                      // half-0 (x + A) ready

    floatx4 acc[4][2][2];                 // [m: co16][p: row][h: q-half]
#pragma unroll
    for (int m = 0; m < 4; ++m)
#pragma unroll
        for (int p = 0; p < 2; ++p)
#pragma unroll
            for (int h = 0; h < 2; ++h)
                acc[m][p][h] = (floatx4){0.f, 0.f, 0.f, 0.f};

    // ---- phases 0..8 (cb = 0): pure LDS + MFMA ----
#pragma unroll 2
    for (int t = 0; t < 9; ++t) {
        const int kh = t / 3;
        const int kw = t - kh * 3;

        short8 a[4];
#pragma unroll
        for (int m = 0; m < 4; ++m)
            a[m] = *reinterpret_cast<const short8*>(
                &af_lds[(t << 8) + (m << 6) + lane]);
        short8 bf[2][2];
#pragma unroll
        for (int p = 0; p < 2; ++p)
#pragma unroll
            for (int h = 0; h < 2; ++h) {
                int prl = (wv << 1) + p + kh;          // 0..9
                int cl  = (h << 4) + l15 + kw;         // 0..33
                int pix = prl * 34 + cl;
                int off = (pix << 4) +
                          ((kg << 2) ^ (((pix >> 1) & 3) << 2));
                bf[p][h] = *(const short8*)(&xs[off]);
            }
        __builtin_amdgcn_s_setprio(1);
#pragma unroll
        for (int m = 0; m < 4; ++m)
#pragma unroll
            for (int p = 0; p < 2; ++p)
#pragma unroll
                for (int h = 0; h < 2; ++h)
                    acc[m][p][h] = __builtin_amdgcn_mfma_f32_16x16x32_bf16(
                        a[m], bf[p][h], acc[m][p][h], 0, 0, 0);
        __builtin_amdgcn_s_setprio(0);
    }
    __syncthreads();                      // WAR: all reads of af_lds/xs0 done

    // ---- WRITE x half 1 + A half 1 ----
#pragma unroll
    for (int r = 0; r < 6; ++r) {
        int u  = r * 256 + tid;
        int uc = u < 1440 ? u : 1439;
        int cp    = uc / 90;
        int rem   = uc - cp * 90;
        int row   = rem / 9;
        int chunk = rem - row * 9;
        int c4 = chunk << 2;
#pragma unroll
        for (int j = 0; j < 4; ++j) {
            if (u < 1440 && c4 + j < 34) {
                int pix = row * 34 + c4 + j;
                int slot = cp ^ (((pix >> 1) & 3) << 2);
                xs[5440 + (pix << 4) + slot] =
                    f2bf_pack(vb[r][0][j], vb[r][1][j]);
            }
        }
    }
#pragma unroll
    for (int i = 0; i < 9; ++i)
        af_lds[i * 256 + tid] = vc[i];
    __syncthreads();                      // half-1 (x + A) ready

    // ---- phases 9..17 (cb = 1): pure LDS + MFMA ----
#pragma unroll 2
    for (int t = 0; t < 9; ++t) {
        const int kh = t / 3;
        const int kw = t - kh * 3;

        short8 a[4];
#pragma unroll
        for (int m = 0; m < 4; ++m)
            a[m] = *reinterpret_cast<const short8*>(
                &af_lds[(t << 8) + (m << 6) + lane]);
        short8 bf[2][2];
#pragma unroll
        for (int p = 0; p < 2; ++p)
#pragma unroll
            for (int h = 0; h < 2; ++h) {
                int prl = (wv << 1) + p + kh;
                int cl  = (h << 4) + l15 + kw;
                int pix = prl * 34 + cl;
                int off = 5440 + (pix << 4) +
                          ((kg << 2) ^ (((pix >> 1) & 3) << 2));
                bf[p][h] = *(const short8*)(&xs[off]);
            }
        __builtin_amdgcn_s_setprio(1);
#pragma unroll
        for (int m = 0; m < 4; ++m)
#pragma unroll
            for (int p = 0; p < 2; ++p)
#pragma unroll
                for (int h = 0; h < 2; ++h)
                    acc[m][p][h] = __builtin_amdgcn_mfma_f32_16x16x32_bf16(
                        a[m], bf[p][h], acc[m][p][h], 0, 0, 0);
        __builtin_amdgcn_s_setprio(0);
    }
    __syncthreads();                      // all waves done reading xs

    // ---- epilogue: per-wave ping-pong slabs overlaid on xs, no barriers ----
    // D layout (m89): col = lane&15 -> q, row = (lane>>4)*4+reg -> co-within-16
    float* epb = reinterpret_cast<float*>(xs);
    const int co_l = lane >> 3;           // 0..7
    const int q4   = lane & 7;

#pragma unroll
    for (int p = 0; p < 2; ++p) {
        const int pr = prb + p;
#pragma unroll
        for (int m = 0; m < 4; ++m) {
            float* ep = epb + (((wv << 1) + (m & 1)) * 576);
#pragma unroll
            for (int h = 0; h < 2; ++h)
#pragma unroll
                for (int reg = 0; reg < 4; ++reg)
                    ep[((kg << 2) + reg) * 36 + (h << 4) + l15] =
                        acc[m][p][h][reg] * cf[p][h];
            // wave-internal RAW through LDS: compiler-inserted lgkmcnt orders
#pragma unroll
            for (int j = 0; j < 2; ++j) {
                const floatx4 v = *reinterpret_cast<const floatx4*>(
                    &ep[(co_l + (j << 3)) * 36 + (q4 << 2)]);
                const int co = (m << 4) + co_l + (j << 3);
                *(floatx4*)(out + (((b << 6) + co) << 16) +
                            (pr << 8) + Q0 + (q4 << 2)) = v;
            }
        }
    }
}

extern "C" void kernel_launch(void* const* d_in, const int* in_sizes, int n_in,
                              void* d_out, int out_size, void* d_ws, size_t ws_size,
                              hipStream_t stream) {
    const float* x     = (const float*)d_in[0];
    const float* wgt   = (const float*)d_in[1];
    const int*   h_idx = (const int*)d_in[2];
    const int*   w_idx = (const int*)d_in[3];
    const float* lam   = (const float*)d_in[4];
    float*       out   = (float*)d_out;
    float*       coeff = (float*)d_ws;                        // 256 KB
    char*        af_b  = (char*)d_ws + 65536 * sizeof(float); // 72 KB
    const int    T     = in_sizes[2];

    srconv_coeff_kernel<<<256, 256, 0, stream>>>(h_idx, w_idx, lam, T, coeff);
    srconv_wtrans_kernel<<<18, 256, 0, stream>>>(wgt, (uint4v*)af_b);
    // 4096 blocks = (32 p-tiles x 8 q-tiles) x 16 batches, XCD-swizzled
    srconv_fused_kernel<<<4096, 256, 0, stream>>>(
        x, coeff, (const uint4v*)af_b, out);
}